// Round 1
// baseline (1075.083 us; speedup 1.0000x reference)
//
#include <hip/hip_runtime.h>
#include <math.h>

// Problem constants (fixed by reference)
constexpr int B    = 32;
constexpr int C    = 384;
constexpr int Himg = 32;
constexpr int Wimg = 32;
constexpr int N    = Himg * Wimg;   // 1024
constexpr int S    = 4;             // area split
constexpr int Ne   = N / S;         // 256 tokens per chunk
constexpr int HEADS= 6;
constexpr int HD   = C / HEADS;     // 64
constexpr int Beff = B * S;         // 128

// ---------------------------------------------------------------------------
// GEMM: Out[b, o, n] = sum_c Wm[o, c] * X[b, c, n]
// Tile: 128 (o) x 64 (n), K-step 16, 256 threads, micro-tile 8x4 per thread.
// grid (N/64, C/128, B)
// ---------------------------------------------------------------------------
__global__ __launch_bounds__(256) void gemm_cn(const float* __restrict__ Wm,
                                               const float* __restrict__ X,
                                               float* __restrict__ Out)
{
    __shared__ float Ws[16][132];   // [k][o] tile, padded
    __shared__ float Xs[16][68];    // [k][n] tile, padded

    const int tid = threadIdx.x;
    const int n0  = blockIdx.x * 64;
    const int o0  = blockIdx.y * 128;
    const int b   = blockIdx.z;
    const float* Xb = X + (size_t)b * C * N;

    const int tm = tid >> 4;   // 0..15 -> rows tm*8..tm*8+7
    const int tn = tid & 15;   // 0..15 -> cols tn*4..tn*4+3

    float acc[8][4] = {};

    for (int k0 = 0; k0 < C; k0 += 16) {
        {   // load W tile: 128 o x 16 k
            const int j  = tid & 15;
            const int i0 = tid >> 4;
            #pragma unroll
            for (int r = 0; r < 8; ++r)
                Ws[j][i0 + 16 * r] = Wm[(size_t)(o0 + i0 + 16 * r) * C + k0 + j];
        }
        {   // load X tile: 16 k x 64 n
            const int n  = tid & 63;
            const int k1 = tid >> 6;
            #pragma unroll
            for (int r = 0; r < 4; ++r)
                Xs[k1 + 4 * r][n] = Xb[(size_t)(k0 + k1 + 4 * r) * N + n0 + n];
        }
        __syncthreads();
        #pragma unroll
        for (int kk = 0; kk < 16; ++kk) {
            float a[8], bb[4];
            *(float4*)&a[0] = *(const float4*)&Ws[kk][tm * 8];
            *(float4*)&a[4] = *(const float4*)&Ws[kk][tm * 8 + 4];
            *(float4*)&bb[0] = *(const float4*)&Xs[kk][tn * 4];
            #pragma unroll
            for (int i = 0; i < 8; ++i)
                #pragma unroll
                for (int j = 0; j < 4; ++j)
                    acc[i][j] += a[i] * bb[j];
        }
        __syncthreads();
    }

    #pragma unroll
    for (int i = 0; i < 8; ++i) {
        float4 o = make_float4(acc[i][0], acc[i][1], acc[i][2], acc[i][3]);
        *(float4*)(Out + ((size_t)b * C + o0 + tm * 8 + i) * N + n0 + tn * 4) = o;
    }
}

// ---------------------------------------------------------------------------
// Depthwise 3x3 (SAME, zero-pad) positional encoding; vpe = v + conv(v, Wpe)
// grid (B*C), 256 threads, 4 pixels/thread.
// ---------------------------------------------------------------------------
__global__ __launch_bounds__(256) void pe_conv(const float* __restrict__ v,
                                               const float* __restrict__ Wpe,
                                               float* __restrict__ vpe)
{
    const int bc = blockIdx.x;         // b*C + c
    const int c  = bc % C;
    const float* wp = Wpe + (size_t)c * 9;
    float wreg[9];
    #pragma unroll
    for (int i = 0; i < 9; ++i) wreg[i] = wp[i];

    const size_t base = (size_t)bc * N;
    const int tid = threadIdx.x;

    #pragma unroll
    for (int r = 0; r < 4; ++r) {
        const int pix = tid + r * 256;
        const int h = pix >> 5, w = pix & 31;
        float acc = v[base + pix];
        #pragma unroll
        for (int dh = -1; dh <= 1; ++dh) {
            const int hh = h + dh;
            if ((unsigned)hh < 32u) {
                #pragma unroll
                for (int dw = -1; dw <= 1; ++dw) {
                    const int ww = w + dw;
                    if ((unsigned)ww < 32u)
                        acc += wreg[(dh + 1) * 3 + (dw + 1)] * v[base + hh * 32 + ww];
                }
            }
        }
        vpe[base + pix] = acc;
    }
}

// ---------------------------------------------------------------------------
// Flash-style attention per (be, head, 32-row q tile).
// q: [Be,h,Ne,hd] = qbuf[b, h*64+d, s*256+ne]; k: [Be,h,hd,Ne]; v likewise.
// Online softmax over m (256 keys, 4 tiles of 64). Output scattered with the
// torch-faithful scramble:
//   fl = (h*64+d)*256 + ne ; ne2 = fl/384 ; c2 = fl%384
//   avs[b, c2, ne2*4 + s]  (layout [B, C, N])
// grid (Ne/32, HEADS, Beff), 256 threads; each thread owns 2 rows x 4 cols.
// ---------------------------------------------------------------------------
__global__ __launch_bounds__(256) void attn_kernel(const float* __restrict__ qb,
                                                   const float* __restrict__ kb,
                                                   const float* __restrict__ vb,
                                                   float* __restrict__ avs)
{
    __shared__ float qs[32][68];   // [ne][d], pre-scaled by 1/8
    __shared__ float kv[64][68];   // K phase: [d][m]; V phase: [m][d]
    __shared__ float Ps[32][68];   // [ne][m] exp weights

    const int tid  = threadIdx.x;
    const int nt   = blockIdx.x;       // 0..7
    const int head = blockIdx.y;       // 0..5
    const int be   = blockIdx.z;       // 0..127
    const int b = be >> 2, s = be & 3;
    const int ch0 = head * HD;
    const int t0  = s * Ne;
    const int ne0 = nt * 32;
    const size_t base = ((size_t)(b * C + ch0)) * N + t0;

    {   // load q tile, scaled by hd^-0.5 = 0.125
        const int ne = tid & 31, d0 = tid >> 5;
        #pragma unroll
        for (int r = 0; r < 8; ++r) {
            const int d = d0 + r * 8;
            qs[ne][d] = qb[base + (size_t)d * N + ne0 + ne] * 0.125f;
        }
    }

    const int tm = tid >> 4;   // 0..15 -> rows tm*2, tm*2+1
    const int tn = tid & 15;   // 0..15 -> cols tn*4..tn*4+3

    float acc[2][4] = {};
    float runmax[2] = {-1e30f, -1e30f};
    float runsum[2] = {0.f, 0.f};

    for (int mt = 0; mt < 4; ++mt) {
        const int m0 = mt * 64;
        __syncthreads();   // previous PV done with kv & Ps
        {   // K tile: kv[d][m]
            const int m = tid & 63, d0 = tid >> 6;
            #pragma unroll
            for (int r = 0; r < 16; ++r) {
                const int d = d0 + r * 4;
                kv[d][m] = kb[base + (size_t)d * N + m0 + m];
            }
        }
        __syncthreads();

        // S tile: sv[i][j] = sum_d q[row][d] * k[d][col]
        float sv[2][4] = {};
        #pragma unroll
        for (int kk = 0; kk < 64; kk += 4) {
            float a[2][4], bb[4][4];
            *(float4*)a[0] = *(const float4*)&qs[tm * 2 + 0][kk];
            *(float4*)a[1] = *(const float4*)&qs[tm * 2 + 1][kk];
            #pragma unroll
            for (int q4 = 0; q4 < 4; ++q4)
                *(float4*)bb[q4] = *(const float4*)&kv[kk + q4][tn * 4];
            #pragma unroll
            for (int q4 = 0; q4 < 4; ++q4)
                #pragma unroll
                for (int i = 0; i < 2; ++i)
                    #pragma unroll
                    for (int j = 0; j < 4; ++j)
                        sv[i][j] += a[i][q4] * bb[q4][j];
        }

        // online softmax update (row groups = 16 lanes sharing tm)
        float p[2][4];
        #pragma unroll
        for (int i = 0; i < 2; ++i) {
            float mx = fmaxf(fmaxf(sv[i][0], sv[i][1]), fmaxf(sv[i][2], sv[i][3]));
            #pragma unroll
            for (int off = 1; off < 16; off <<= 1)
                mx = fmaxf(mx, __shfl_xor(mx, off));
            const float nm = fmaxf(runmax[i], mx);
            const float sc = __expf(runmax[i] - nm);
            runmax[i] = nm;
            runsum[i] *= sc;
            #pragma unroll
            for (int j = 0; j < 4; ++j) acc[i][j] *= sc;
            float ls = 0.f;
            #pragma unroll
            for (int j = 0; j < 4; ++j) { p[i][j] = __expf(sv[i][j] - nm); ls += p[i][j]; }
            #pragma unroll
            for (int off = 1; off < 16; off <<= 1)
                ls += __shfl_xor(ls, off);
            runsum[i] += ls;
        }
        // stash P tile
        *(float4*)&Ps[tm * 2 + 0][tn * 4] = *(float4*)p[0];
        *(float4*)&Ps[tm * 2 + 1][tn * 4] = *(float4*)p[1];

        __syncthreads();   // done reading kv (K), Ps written
        {   // V tile: kv[m][d]
            const int m = tid & 63, d0 = tid >> 6;
            #pragma unroll
            for (int r = 0; r < 16; ++r) {
                const int d = d0 + r * 4;
                kv[m][d] = vb[base + (size_t)d * N + m0 + m];
            }
        }
        __syncthreads();

        // PV: acc[i][j] += sum_m P[row][m] * v[m][col]
        #pragma unroll
        for (int mm = 0; mm < 64; mm += 4) {
            float a[2][4], bb[4][4];
            *(float4*)a[0] = *(const float4*)&Ps[tm * 2 + 0][mm];
            *(float4*)a[1] = *(const float4*)&Ps[tm * 2 + 1][mm];
            #pragma unroll
            for (int q4 = 0; q4 < 4; ++q4)
                *(float4*)bb[q4] = *(const float4*)&kv[mm + q4][tn * 4];
            #pragma unroll
            for (int q4 = 0; q4 < 4; ++q4)
                #pragma unroll
                for (int i = 0; i < 2; ++i)
                    #pragma unroll
                    for (int j = 0; j < 4; ++j)
                        acc[i][j] += a[i][q4] * bb[q4][j];
        }
    }

    // normalize + scrambled scatter-store
    const float inv0 = 1.f / runsum[0];
    const float inv1 = 1.f / runsum[1];
    #pragma unroll
    for (int i = 0; i < 2; ++i) {
        const int ne_full = ne0 + tm * 2 + i;
        const float inv = i ? inv1 : inv0;
        #pragma unroll
        for (int j = 0; j < 4; ++j) {
            const int d  = tn * 4 + j;
            const int fl = (ch0 + d) * Ne + ne_full;   // < 98304
            const int ne2 = fl / 384;
            const int c2  = fl - ne2 * 384;
            avs[((size_t)b * C + c2) * N + (ne2 << 2) + s] = acc[i][j] * inv;
        }
    }
}

// ---------------------------------------------------------------------------
// BatchNorm stats: one block per channel, biased variance.
// ---------------------------------------------------------------------------
__global__ __launch_bounds__(256) void bnstats(const float* __restrict__ pre,
                                               float* __restrict__ mean,
                                               float* __restrict__ rstd)
{
    const int o = blockIdx.x;
    const int tid = threadIdx.x;
    float s1 = 0.f, s2 = 0.f;
    for (int idx = tid; idx < B * N; idx += 256) {
        const int bb = idx >> 10, n = idx & 1023;
        const float v = pre[((size_t)bb * C + o) * N + n];
        s1 += v;
        s2 += v * v;
    }
    #pragma unroll
    for (int off = 32; off > 0; off >>= 1) {
        s1 += __shfl_down(s1, off);
        s2 += __shfl_down(s2, off);
    }
    __shared__ float r1[4], r2[4];
    const int w = tid >> 6;
    if ((tid & 63) == 0) { r1[w] = s1; r2[w] = s2; }
    __syncthreads();
    if (tid == 0) {
        const float t1 = r1[0] + r1[1] + r1[2] + r1[3];
        const float t2 = r2[0] + r2[1] + r2[2] + r2[3];
        const float mu = t1 * (1.f / (B * N));
        const float var = t2 * (1.f / (B * N)) - mu * mu;
        mean[o] = mu;
        rstd[o] = rsqrtf(var + 1e-5f);
    }
}

// ---------------------------------------------------------------------------
// Finalize: out = x + gamma*(pre-mu)*rstd + beta   (float4 vectorized)
// ---------------------------------------------------------------------------
__global__ __launch_bounds__(256) void finalize(const float* __restrict__ x,
                                                const float* __restrict__ pre,
                                                const float* __restrict__ mean,
                                                const float* __restrict__ rstd,
                                                const float* __restrict__ gamma,
                                                const float* __restrict__ beta,
                                                float* __restrict__ out)
{
    const size_t i = (size_t)blockIdx.x * 256 + threadIdx.x;
    const size_t e = i << 2;
    const int c = (int)((e >> 10) % C);
    const float4 xv = *(const float4*)(x + e);
    const float4 pv = *(const float4*)(pre + e);
    const float mu = mean[c], rs = rstd[c], g = gamma[c], bt = beta[c];
    float4 o;
    o.x = xv.x + g * (pv.x - mu) * rs + bt;
    o.y = xv.y + g * (pv.y - mu) * rs + bt;
    o.z = xv.z + g * (pv.z - mu) * rs + bt;
    o.w = xv.w + g * (pv.w - mu) * rs + bt;
    *(float4*)(out + e) = o;
}

// ---------------------------------------------------------------------------
extern "C" void kernel_launch(void* const* d_in, const int* in_sizes, int n_in,
                              void* d_out, int out_size, void* d_ws, size_t ws_size,
                              hipStream_t stream)
{
    const float* x     = (const float*)d_in[0];
    const float* Wq    = (const float*)d_in[1];
    const float* Wk    = (const float*)d_in[2];
    const float* Wv    = (const float*)d_in[3];
    const float* Wpe   = (const float*)d_in[4];
    const float* Wproj = (const float*)d_in[5];
    const float* gamma = (const float*)d_in[6];
    const float* beta  = (const float*)d_in[7];
    float* out = (float*)d_out;

    float* ws = (float*)d_ws;
    const size_t SZ = (size_t)B * C * N;      // 12,582,912 floats
    float* qb   = ws;
    float* kb   = ws + SZ;
    float* vb   = ws + 2 * SZ;
    float* vpeb = ws + 3 * SZ;
    float* avs  = vb;    // v(raw) dead after pe_conv
    float* pre  = qb;    // q dead after attention
    float* mean = ws + 4 * SZ;
    float* rstd = mean + C;

    const dim3 gg(N / 64, C / 128, B);
    gemm_cn<<<gg, 256, 0, stream>>>(Wq, x, qb);
    gemm_cn<<<gg, 256, 0, stream>>>(Wk, x, kb);
    gemm_cn<<<gg, 256, 0, stream>>>(Wv, x, vb);
    pe_conv<<<B * C, 256, 0, stream>>>(vb, Wpe, vpeb);
    attn_kernel<<<dim3(Ne / 32, HEADS, Beff), 256, 0, stream>>>(qb, kb, vpeb, avs);
    gemm_cn<<<gg, 256, 0, stream>>>(Wproj, avs, pre);
    bnstats<<<C, 256, 0, stream>>>(pre, mean, rstd);
    finalize<<<(int)(SZ / 4 / 256), 256, 0, stream>>>(x, pre, mean, rstd, gamma, beta, out);
}

// Round 3
// 648.113 us; speedup vs baseline: 1.6588x; 1.6588x over previous
//
#include <hip/hip_runtime.h>
#include <math.h>

// Problem constants (fixed by reference)
constexpr int B    = 32;
constexpr int C    = 384;
constexpr int N    = 1024;          // 32*32
constexpr int S    = 4;
constexpr int Ne   = N / S;         // 256
constexpr int HEADS= 6;
constexpr int HD   = C / HEADS;     // 64

typedef __attribute__((ext_vector_type(8))) short bf16x8;
typedef __attribute__((ext_vector_type(4))) float f32x4;

__device__ __forceinline__ unsigned short f2bf(float f) {
    unsigned int u = __float_as_uint(f);
    u = (u + 0x7fff + ((u >> 16) & 1)) >> 16;   // round-to-nearest-even
    return (unsigned short)u;
}

__device__ __forceinline__ void async16(const void* g, void* l) {
    __builtin_amdgcn_global_load_lds(
        (const __attribute__((address_space(1))) void*)g,
        (__attribute__((address_space(3))) void*)l, 16, 0, 0);
}

// ---------------------------------------------------------------------------
// Cast the 4 [384x384] fp32 weight matrices to bf16 (same [o][c] layout).
// grid (144, 4): 147456/4/256 = 144 blocks per matrix.
// ---------------------------------------------------------------------------
__global__ __launch_bounds__(256) void cast_weights(const float* __restrict__ Wq,
                                                    const float* __restrict__ Wk,
                                                    const float* __restrict__ Wv,
                                                    const float* __restrict__ Wp,
                                                    unsigned short* __restrict__ out)
{
    const int sel = blockIdx.y;
    const float* src = sel == 0 ? Wq : sel == 1 ? Wk : sel == 2 ? Wv : Wp;
    unsigned short* dst = out + (size_t)sel * (C * C);
    const int i = (blockIdx.x * 256 + threadIdx.x) * 4;
    const float4 v = *(const float4*)&src[i];
    ushort4 o;
    o.x = f2bf(v.x); o.y = f2bf(v.y); o.z = f2bf(v.z); o.w = f2bf(v.w);
    *(ushort4*)&dst[i] = o;
}

// ---------------------------------------------------------------------------
// Transpose-cast: x[b][c][n] fp32 -> xt[b][n][c] bf16 (32x32 LDS tiles).
// grid (N/32, C/32, B) = (32, 12, 32)
// ---------------------------------------------------------------------------
__global__ __launch_bounds__(256) void cast_xt(const float* __restrict__ x,
                                               unsigned short* __restrict__ xt)
{
    __shared__ float T[32][33];
    const int n0 = blockIdx.x * 32;
    const int c0 = blockIdx.y * 32;
    const int b  = blockIdx.z;
    const int tid = threadIdx.x;
    {
        const int ci = tid >> 3;
        const int nj = (tid & 7) * 4;
        const float4 v = *(const float4*)&x[((size_t)b * C + c0 + ci) * N + n0 + nj];
        T[ci][nj] = v.x; T[ci][nj + 1] = v.y; T[ci][nj + 2] = v.z; T[ci][nj + 3] = v.w;
    }
    __syncthreads();
    {
        const int ni = tid >> 3;
        const int cj = (tid & 7) * 4;
        ushort4 o;
        o.x = f2bf(T[cj + 0][ni]);
        o.y = f2bf(T[cj + 1][ni]);
        o.z = f2bf(T[cj + 2][ni]);
        o.w = f2bf(T[cj + 3][ni]);
        *(ushort4*)&xt[((size_t)b * N + n0 + ni) * C + c0 + cj] = o;
    }
}

// ---------------------------------------------------------------------------
// bf16 MFMA GEMM (m97 structure): Out[b][o][n] = sum_c A[o][c] * Bt[b][n][c]
// A: [384][384] bf16 row-major; Bt: [32][1024][384] bf16 (K contiguous).
// 128x128 tile, BK=32, 256 threads (4 waves 2x2), 16x16x32 bf16 MFMA,
// global_load_lds width-16 staging, 2 barriers per K-step.
// grid (N/128, 384/128, B) = (8, 3, 32)
// ---------------------------------------------------------------------------
__global__ __launch_bounds__(256) void gemm_bt(const unsigned short* __restrict__ A,
                                               const unsigned short* __restrict__ Bt,
                                               float* __restrict__ Out)
{
    __shared__ short As[128 * 32];   // [o-row][k] 64B rows
    __shared__ short Bs[128 * 32];   // [n-row][k] 64B rows

    const int tid  = threadIdx.x;
    const int lane = tid & 63;
    const int wid  = tid >> 6;
    const int n0 = blockIdx.x * 128;
    const int o0 = blockIdx.y * 128;
    const int b  = blockIdx.z;
    const int wr = wid >> 1;         // wave row (M half)
    const int wc = wid & 1;          // wave col (N half)

    const unsigned short* Bb = Bt + (size_t)b * N * C;

    f32x4 acc[4][4];
    #pragma unroll
    for (int i = 0; i < 4; ++i)
        #pragma unroll
        for (int j = 0; j < 4; ++j)
            acc[i][j] = (f32x4){0.f, 0.f, 0.f, 0.f};

    const int lr = lane & 15;
    const int lk = (lane >> 4) * 8;

    for (int k0 = 0; k0 < C; k0 += 32) {
        // stage A,B tiles: 8KB each; 512 16B-chunks; 2 issues x 256 threads
        #pragma unroll
        for (int r = 0; r < 2; ++r) {
            const int ci   = r * 256 + tid;            // chunk 0..511
            const int row  = ci >> 2;                  // 64B rows (BK=32 bf16)
            const int ck   = (ci & 3) * 8;             // k element offset
            const int lbase = (r * 256 + (wid << 6)) << 3;  // wave-uniform, shorts
            async16(A  + (size_t)(o0 + row) * C + k0 + ck, &As[lbase]);
            async16(Bb + (size_t)(n0 + row) * C + k0 + ck, &Bs[lbase]);
        }
        __syncthreads();   // compiler drains vmcnt before barrier

        bf16x8 af[4], bfr[4];
        #pragma unroll
        for (int i = 0; i < 4; ++i) {
            af[i]  = *(const bf16x8*)&As[(wr * 64 + i * 16 + lr) * 32 + lk];
            bfr[i] = *(const bf16x8*)&Bs[(wc * 64 + i * 16 + lr) * 32 + lk];
        }
        #pragma unroll
        for (int mi = 0; mi < 4; ++mi)
            #pragma unroll
            for (int ni = 0; ni < 4; ++ni)
                acc[mi][ni] = __builtin_amdgcn_mfma_f32_16x16x32_bf16(
                    af[mi], bfr[ni], acc[mi][ni], 0, 0, 0);
        __syncthreads();   // compute done before next stage overwrites
    }

    // epilogue: C/D layout col=lane&15, row=(lane>>4)*4+reg
    const int dc = lane & 15;
    const int dr = (lane >> 4) * 4;
    float* Ob = Out + ((size_t)b * C + o0 + wr * 64) * N + n0 + wc * 64;
    #pragma unroll
    for (int mi = 0; mi < 4; ++mi)
        #pragma unroll
        for (int ni = 0; ni < 4; ++ni) {
            const f32x4 v = acc[mi][ni];
            #pragma unroll
            for (int r = 0; r < 4; ++r)
                Ob[(size_t)(mi * 16 + dr + r) * N + ni * 16 + dc] = v[r];
        }
}

// ---------------------------------------------------------------------------
// Depthwise 3x3 (SAME) positional encoding; vpe = v + conv(v, Wpe)   (fp32)
// ---------------------------------------------------------------------------
__global__ __launch_bounds__(256) void pe_conv(const float* __restrict__ v,
                                               const float* __restrict__ Wpe,
                                               float* __restrict__ vpe)
{
    const int bc = blockIdx.x;
    const int c  = bc % C;
    const float* wp = Wpe + (size_t)c * 9;
    float wreg[9];
    #pragma unroll
    for (int i = 0; i < 9; ++i) wreg[i] = wp[i];

    const size_t base = (size_t)bc * N;
    const int tid = threadIdx.x;

    #pragma unroll
    for (int r = 0; r < 4; ++r) {
        const int pix = tid + r * 256;
        const int h = pix >> 5, w = pix & 31;
        float acc = v[base + pix];
        #pragma unroll
        for (int dh = -1; dh <= 1; ++dh) {
            const int hh = h + dh;
            if ((unsigned)hh < 32u) {
                #pragma unroll
                for (int dw = -1; dw <= 1; ++dw) {
                    const int ww = w + dw;
                    if ((unsigned)ww < 32u)
                        acc += wreg[(dh + 1) * 3 + (dw + 1)] * v[base + hh * 32 + ww];
                }
            }
        }
        vpe[base + pix] = acc;
    }
}

// ---------------------------------------------------------------------------
// Flash-style fp32 attention (unchanged math). Output stored bf16 in the
// proj-GEMM's Bt layout: avst[b][n][c] with n = ne2*4+s, c = c2.
// grid (Ne/32, HEADS, 128), 256 threads.
// ---------------------------------------------------------------------------
__global__ __launch_bounds__(256) void attn_kernel(const float* __restrict__ qb,
                                                   const float* __restrict__ kb,
                                                   const float* __restrict__ vb,
                                                   unsigned short* __restrict__ avst)
{
    __shared__ float qs[32][68];
    __shared__ float kv[64][68];
    __shared__ float Ps[32][68];

    const int tid  = threadIdx.x;
    const int nt   = blockIdx.x;
    const int head = blockIdx.y;
    const int be   = blockIdx.z;
    const int b = be >> 2, s = be & 3;
    const int ch0 = head * HD;
    const int t0  = s * Ne;
    const int ne0 = nt * 32;
    const size_t base = ((size_t)(b * C + ch0)) * N + t0;

    {
        const int ne = tid & 31, d0 = tid >> 5;
        #pragma unroll
        for (int r = 0; r < 8; ++r) {
            const int d = d0 + r * 8;
            qs[ne][d] = qb[base + (size_t)d * N + ne0 + ne] * 0.125f;
        }
    }

    const int tm = tid >> 4;
    const int tn = tid & 15;

    float acc[2][4] = {};
    float runmax[2] = {-1e30f, -1e30f};
    float runsum[2] = {0.f, 0.f};

    for (int mt = 0; mt < 4; ++mt) {
        const int m0 = mt * 64;
        __syncthreads();
        {
            const int m = tid & 63, d0 = tid >> 6;
            #pragma unroll
            for (int r = 0; r < 16; ++r) {
                const int d = d0 + r * 4;
                kv[d][m] = kb[base + (size_t)d * N + m0 + m];
            }
        }
        __syncthreads();

        float sv[2][4] = {};
        #pragma unroll
        for (int kk = 0; kk < 64; kk += 4) {
            float a[2][4], bb[4][4];
            *(float4*)a[0] = *(const float4*)&qs[tm * 2 + 0][kk];
            *(float4*)a[1] = *(const float4*)&qs[tm * 2 + 1][kk];
            #pragma unroll
            for (int q4 = 0; q4 < 4; ++q4)
                *(float4*)bb[q4] = *(const float4*)&kv[kk + q4][tn * 4];
            #pragma unroll
            for (int q4 = 0; q4 < 4; ++q4)
                #pragma unroll
                for (int i = 0; i < 2; ++i)
                    #pragma unroll
                    for (int j = 0; j < 4; ++j)
                        sv[i][j] += a[i][q4] * bb[q4][j];
        }

        float p[2][4];
        #pragma unroll
        for (int i = 0; i < 2; ++i) {
            float mx = fmaxf(fmaxf(sv[i][0], sv[i][1]), fmaxf(sv[i][2], sv[i][3]));
            #pragma unroll
            for (int off = 1; off < 16; off <<= 1)
                mx = fmaxf(mx, __shfl_xor(mx, off));
            const float nm = fmaxf(runmax[i], mx);
            const float sc = __expf(runmax[i] - nm);
            runmax[i] = nm;
            runsum[i] *= sc;
            #pragma unroll
            for (int j = 0; j < 4; ++j) acc[i][j] *= sc;
            float ls = 0.f;
            #pragma unroll
            for (int j = 0; j < 4; ++j) { p[i][j] = __expf(sv[i][j] - nm); ls += p[i][j]; }
            #pragma unroll
            for (int off = 1; off < 16; off <<= 1)
                ls += __shfl_xor(ls, off);
            runsum[i] += ls;
        }
        *(float4*)&Ps[tm * 2 + 0][tn * 4] = *(float4*)p[0];
        *(float4*)&Ps[tm * 2 + 1][tn * 4] = *(float4*)p[1];

        __syncthreads();
        {
            const int m = tid & 63, d0 = tid >> 6;
            #pragma unroll
            for (int r = 0; r < 16; ++r) {
                const int d = d0 + r * 4;
                kv[m][d] = vb[base + (size_t)d * N + m0 + m];
            }
        }
        __syncthreads();

        #pragma unroll
        for (int mm = 0; mm < 64; mm += 4) {
            float a[2][4], bb[4][4];
            *(float4*)a[0] = *(const float4*)&Ps[tm * 2 + 0][mm];
            *(float4*)a[1] = *(const float4*)&Ps[tm * 2 + 1][mm];
            #pragma unroll
            for (int q4 = 0; q4 < 4; ++q4)
                *(float4*)bb[q4] = *(const float4*)&kv[mm + q4][tn * 4];
            #pragma unroll
            for (int q4 = 0; q4 < 4; ++q4)
                #pragma unroll
                for (int i = 0; i < 2; ++i)
                    #pragma unroll
                    for (int j = 0; j < 4; ++j)
                        acc[i][j] += a[i][q4] * bb[q4][j];
        }
    }

    const float inv0 = 1.f / runsum[0];
    const float inv1 = 1.f / runsum[1];
    #pragma unroll
    for (int i = 0; i < 2; ++i) {
        const int ne_full = ne0 + tm * 2 + i;
        const float inv = i ? inv1 : inv0;
        #pragma unroll
        for (int j = 0; j < 4; ++j) {
            const int d  = tn * 4 + j;
            const int fl = (ch0 + d) * Ne + ne_full;
            const int ne2 = fl / 384;
            const int c2  = fl - ne2 * 384;
            avst[((size_t)b * N + (ne2 << 2) + s) * C + c2] = f2bf(acc[i][j] * inv);
        }
    }
}

// ---------------------------------------------------------------------------
// BatchNorm stats: one block per channel, biased variance.
// ---------------------------------------------------------------------------
__global__ __launch_bounds__(256) void bnstats(const float* __restrict__ pre,
                                               float* __restrict__ mean,
                                               float* __restrict__ rstd)
{
    const int o = blockIdx.x;
    const int tid = threadIdx.x;
    float s1 = 0.f, s2 = 0.f;
    for (int idx = tid; idx < B * N; idx += 256) {
        const int bb = idx >> 10, n = idx & 1023;
        const float v = pre[((size_t)bb * C + o) * N + n];
        s1 += v;
        s2 += v * v;
    }
    #pragma unroll
    for (int off = 32; off > 0; off >>= 1) {
        s1 += __shfl_down(s1, off);
        s2 += __shfl_down(s2, off);
    }
    __shared__ float r1[4], r2[4];
    const int w = tid >> 6;
    if ((tid & 63) == 0) { r1[w] = s1; r2[w] = s2; }
    __syncthreads();
    if (tid == 0) {
        const float t1 = r1[0] + r1[1] + r1[2] + r1[3];
        const float t2 = r2[0] + r2[1] + r2[2] + r2[3];
        const float mu = t1 * (1.f / (B * N));
        const float var = t2 * (1.f / (B * N)) - mu * mu;
        mean[o] = mu;
        rstd[o] = rsqrtf(var + 1e-5f);
    }
}

// ---------------------------------------------------------------------------
// Finalize: out = x + gamma*(pre-mu)*rstd + beta
// ---------------------------------------------------------------------------
__global__ __launch_bounds__(256) void finalize(const float* __restrict__ x,
                                                const float* __restrict__ pre,
                                                const float* __restrict__ mean,
                                                const float* __restrict__ rstd,
                                                const float* __restrict__ gamma,
                                                const float* __restrict__ beta,
                                                float* __restrict__ out)
{
    const size_t i = (size_t)blockIdx.x * 256 + threadIdx.x;
    const size_t e = i << 2;
    const int c = (int)((e >> 10) % C);
    const float4 xv = *(const float4*)(x + e);
    const float4 pv = *(const float4*)(pre + e);
    const float mu = mean[c], rs = rstd[c], g = gamma[c], bt = beta[c];
    float4 o;
    o.x = xv.x + g * (pv.x - mu) * rs + bt;
    o.y = xv.y + g * (pv.y - mu) * rs + bt;
    o.z = xv.z + g * (pv.z - mu) * rs + bt;
    o.w = xv.w + g * (pv.w - mu) * rs + bt;
    *(float4*)(out + e) = o;
}

// ---------------------------------------------------------------------------
extern "C" void kernel_launch(void* const* d_in, const int* in_sizes, int n_in,
                              void* d_out, int out_size, void* d_ws, size_t ws_size,
                              hipStream_t stream)
{
    const float* x     = (const float*)d_in[0];
    const float* Wq    = (const float*)d_in[1];
    const float* Wk    = (const float*)d_in[2];
    const float* Wv    = (const float*)d_in[3];
    const float* Wpe   = (const float*)d_in[4];
    const float* Wproj = (const float*)d_in[5];
    const float* gamma = (const float*)d_in[6];
    const float* beta  = (const float*)d_in[7];
    float* out = (float*)d_out;

    float* ws = (float*)d_ws;
    const size_t SZ = (size_t)B * C * N;      // 12,582,912 floats per region

    // Region A: xt (bf16, first SZ/2 floats) -> later vpeb (fp32, full)
    // Region B: qb (fp32) -> later pre (fp32)
    // Region C: kb (fp32)
    // Region D: vb (fp32) -> later avst (bf16, first SZ/2 floats)
    float* regA = ws;
    float* regB = ws + SZ;
    float* regC = ws + 2 * SZ;
    float* regD = ws + 3 * SZ;
    unsigned short* w16  = (unsigned short*)(ws + 4 * SZ);   // 4 x 147456 bf16
    float* mean = ws + 4 * SZ + 294912;
    float* rstd = mean + C;

    unsigned short* xt   = (unsigned short*)regA;
    float* qb   = regB;
    float* kb   = regC;
    float* vb   = regD;
    float* vpeb = regA;
    unsigned short* avst = (unsigned short*)regD;
    float* pre  = regB;

    cast_weights<<<dim3(144, 4), 256, 0, stream>>>(Wq, Wk, Wv, Wproj, w16);
    cast_xt<<<dim3(32, 12, 32), 256, 0, stream>>>(x, xt);

    const dim3 gg(N / 128, C / 128, B);   // (8, 3, 32)
    gemm_bt<<<gg, 256, 0, stream>>>(w16,               xt, qb);
    gemm_bt<<<gg, 256, 0, stream>>>(w16 + 147456,      xt, kb);
    gemm_bt<<<gg, 256, 0, stream>>>(w16 + 2 * 147456,  xt, vb);
    pe_conv<<<B * C, 256, 0, stream>>>(vb, Wpe, vpeb);
    attn_kernel<<<dim3(Ne / 32, HEADS, 128), 256, 0, stream>>>(qb, kb, vpeb, avst);
    gemm_bt<<<gg, 256, 0, stream>>>(w16 + 3 * 147456, avst, pre);
    bnstats<<<C, 256, 0, stream>>>(pre, mean, rstd);
    finalize<<<(int)(SZ / 4 / 256), 256, 0, stream>>>(x, pre, mean, rstd, gamma, beta, out);
}

// Round 4
// 382.856 us; speedup vs baseline: 2.8081x; 1.6928x over previous
//
#include <hip/hip_runtime.h>
#include <math.h>

// Problem constants (fixed by reference)
constexpr int B    = 32;
constexpr int C    = 384;
constexpr int N    = 1024;          // 32*32
constexpr int S    = 4;
constexpr int Ne   = N / S;         // 256
constexpr int HEADS= 6;
constexpr int HD   = C / HEADS;     // 64

typedef __attribute__((ext_vector_type(8))) short bf16x8;
typedef __attribute__((ext_vector_type(4))) float f32x4;

__device__ __forceinline__ unsigned short f2bf(float f) {
    unsigned int u = __float_as_uint(f);
    u = (u + 0x7fff + ((u >> 16) & 1)) >> 16;   // round-to-nearest-even
    return (unsigned short)u;
}

// pack two positive f32 to packed bf16x2, round-half-up (cheap; P in [0,1])
__device__ __forceinline__ unsigned int pack2(float a, float b) {
    return ((__float_as_uint(a) + 0x8000u) >> 16) |
           ((__float_as_uint(b) + 0x8000u) & 0xffff0000u);
}

__device__ __forceinline__ void async16(const void* g, void* l) {
    __builtin_amdgcn_global_load_lds(
        (const __attribute__((address_space(1))) void*)g,
        (__attribute__((address_space(3))) void*)l, 16, 0, 0);
}

// ---------------------------------------------------------------------------
// Cast the 4 [384x384] fp32 weight matrices to bf16 (same [o][c] layout).
// ---------------------------------------------------------------------------
__global__ __launch_bounds__(256) void cast_weights(const float* __restrict__ Wq,
                                                    const float* __restrict__ Wk,
                                                    const float* __restrict__ Wv,
                                                    const float* __restrict__ Wp,
                                                    unsigned short* __restrict__ out)
{
    const int sel = blockIdx.y;
    const float* src = sel == 0 ? Wq : sel == 1 ? Wk : sel == 2 ? Wv : Wp;
    unsigned short* dst = out + (size_t)sel * (C * C);
    const int i = (blockIdx.x * 256 + threadIdx.x) * 4;
    const float4 v = *(const float4*)&src[i];
    ushort4 o;
    o.x = f2bf(v.x); o.y = f2bf(v.y); o.z = f2bf(v.z); o.w = f2bf(v.w);
    *(ushort4*)&dst[i] = o;
}

// ---------------------------------------------------------------------------
// Transpose-cast: x[b][c][n] fp32 -> xt[b][n][c] bf16 (32x32 LDS tiles).
// ---------------------------------------------------------------------------
__global__ __launch_bounds__(256) void cast_xt(const float* __restrict__ x,
                                               unsigned short* __restrict__ xt)
{
    __shared__ float T[32][33];
    const int n0 = blockIdx.x * 32;
    const int c0 = blockIdx.y * 32;
    const int b  = blockIdx.z;
    const int tid = threadIdx.x;
    {
        const int ci = tid >> 3;
        const int nj = (tid & 7) * 4;
        const float4 v = *(const float4*)&x[((size_t)b * C + c0 + ci) * N + n0 + nj];
        T[ci][nj] = v.x; T[ci][nj + 1] = v.y; T[ci][nj + 2] = v.z; T[ci][nj + 3] = v.w;
    }
    __syncthreads();
    {
        const int ni = tid >> 3;
        const int cj = (tid & 7) * 4;
        ushort4 o;
        o.x = f2bf(T[cj + 0][ni]);
        o.y = f2bf(T[cj + 1][ni]);
        o.z = f2bf(T[cj + 2][ni]);
        o.w = f2bf(T[cj + 3][ni]);
        *(ushort4*)&xt[((size_t)b * N + n0 + ni) * C + c0 + cj] = o;
    }
}

// ---------------------------------------------------------------------------
// bf16 MFMA GEMM, fp32 [b][o][n] output (for v and proj).
// Out[b][o][n] = sum_c A[o][c] * Bt[b][n][c]
// ---------------------------------------------------------------------------
__global__ __launch_bounds__(256) void gemm_bt(const unsigned short* __restrict__ A,
                                               const unsigned short* __restrict__ Bt,
                                               float* __restrict__ Out)
{
    __shared__ short As[128 * 32];
    __shared__ short Bs[128 * 32];

    const int tid  = threadIdx.x;
    const int lane = tid & 63;
    const int wid  = tid >> 6;
    const int n0 = blockIdx.x * 128;
    const int o0 = blockIdx.y * 128;
    const int b  = blockIdx.z;
    const int wr = wid >> 1;
    const int wc = wid & 1;

    const unsigned short* Bb = Bt + (size_t)b * N * C;

    f32x4 acc[4][4];
    #pragma unroll
    for (int i = 0; i < 4; ++i)
        #pragma unroll
        for (int j = 0; j < 4; ++j)
            acc[i][j] = (f32x4){0.f, 0.f, 0.f, 0.f};

    const int lr = lane & 15;
    const int lk = (lane >> 4) * 8;

    for (int k0 = 0; k0 < C; k0 += 32) {
        #pragma unroll
        for (int r = 0; r < 2; ++r) {
            const int ci   = r * 256 + tid;
            const int row  = ci >> 2;
            const int ck   = (ci & 3) * 8;
            const int lbase = (r * 256 + (wid << 6)) << 3;
            async16(A  + (size_t)(o0 + row) * C + k0 + ck, &As[lbase]);
            async16(Bb + (size_t)(n0 + row) * C + k0 + ck, &Bs[lbase]);
        }
        __syncthreads();

        bf16x8 af[4], bfr[4];
        #pragma unroll
        for (int i = 0; i < 4; ++i) {
            af[i]  = *(const bf16x8*)&As[(wr * 64 + i * 16 + lr) * 32 + lk];
            bfr[i] = *(const bf16x8*)&Bs[(wc * 64 + i * 16 + lr) * 32 + lk];
        }
        #pragma unroll
        for (int mi = 0; mi < 4; ++mi)
            #pragma unroll
            for (int ni = 0; ni < 4; ++ni)
                acc[mi][ni] = __builtin_amdgcn_mfma_f32_16x16x32_bf16(
                    af[mi], bfr[ni], acc[mi][ni], 0, 0, 0);
        __syncthreads();
    }

    const int dc = lane & 15;
    const int dr = (lane >> 4) * 4;
    float* Ob = Out + ((size_t)b * C + o0 + wr * 64) * N + n0 + wc * 64;
    #pragma unroll
    for (int mi = 0; mi < 4; ++mi)
        #pragma unroll
        for (int ni = 0; ni < 4; ++ni) {
            const f32x4 v = acc[mi][ni];
            #pragma unroll
            for (int r = 0; r < 4; ++r)
                Ob[(size_t)(mi * 16 + dr + r) * N + ni * 16 + dc] = v[r];
        }
}

// ---------------------------------------------------------------------------
// Same GEMM core, but bf16 [b][n][o] (transposed) output, with scale.
// Used for q (scale=0.125) and k (scale=1): feeds attention fragments directly.
// Epilogue packs 4 consecutive-o bf16 into one 8B store.
// ---------------------------------------------------------------------------
__global__ __launch_bounds__(256) void gemm_qk(const unsigned short* __restrict__ A,
                                               const unsigned short* __restrict__ Bt,
                                               unsigned short* __restrict__ Out,
                                               float scale)
{
    __shared__ short As[128 * 32];
    __shared__ short Bs[128 * 32];

    const int tid  = threadIdx.x;
    const int lane = tid & 63;
    const int wid  = tid >> 6;
    const int n0 = blockIdx.x * 128;
    const int o0 = blockIdx.y * 128;
    const int b  = blockIdx.z;
    const int wr = wid >> 1;
    const int wc = wid & 1;

    const unsigned short* Bb = Bt + (size_t)b * N * C;

    f32x4 acc[4][4];
    #pragma unroll
    for (int i = 0; i < 4; ++i)
        #pragma unroll
        for (int j = 0; j < 4; ++j)
            acc[i][j] = (f32x4){0.f, 0.f, 0.f, 0.f};

    const int lr = lane & 15;
    const int lk = (lane >> 4) * 8;

    for (int k0 = 0; k0 < C; k0 += 32) {
        #pragma unroll
        for (int r = 0; r < 2; ++r) {
            const int ci   = r * 256 + tid;
            const int row  = ci >> 2;
            const int ck   = (ci & 3) * 8;
            const int lbase = (r * 256 + (wid << 6)) << 3;
            async16(A  + (size_t)(o0 + row) * C + k0 + ck, &As[lbase]);
            async16(Bb + (size_t)(n0 + row) * C + k0 + ck, &Bs[lbase]);
        }
        __syncthreads();

        bf16x8 af[4], bfr[4];
        #pragma unroll
        for (int i = 0; i < 4; ++i) {
            af[i]  = *(const bf16x8*)&As[(wr * 64 + i * 16 + lr) * 32 + lk];
            bfr[i] = *(const bf16x8*)&Bs[(wc * 64 + i * 16 + lr) * 32 + lk];
        }
        #pragma unroll
        for (int mi = 0; mi < 4; ++mi)
            #pragma unroll
            for (int ni = 0; ni < 4; ++ni)
                acc[mi][ni] = __builtin_amdgcn_mfma_f32_16x16x32_bf16(
                    af[mi], bfr[ni], acc[mi][ni], 0, 0, 0);
        __syncthreads();
    }

    const int dc = lane & 15;
    const int dr = (lane >> 4) * 4;
    #pragma unroll
    for (int mi = 0; mi < 4; ++mi)
        #pragma unroll
        for (int ni = 0; ni < 4; ++ni) {
            const f32x4 v = acc[mi][ni];
            ushort4 pk;
            pk.x = f2bf(v[0] * scale);
            pk.y = f2bf(v[1] * scale);
            pk.z = f2bf(v[2] * scale);
            pk.w = f2bf(v[3] * scale);
            const int nrow = n0 + wc * 64 + ni * 16 + dc;
            const int ocol = o0 + wr * 64 + mi * 16 + dr;
            *(ushort4*)&Out[((size_t)b * N + nrow) * C + ocol] = pk;
        }
}

// ---------------------------------------------------------------------------
// Depthwise 3x3 (SAME) PE; vpe = v + conv(v, Wpe). fp32 in, bf16 out [b][c][n]
// (this layout is exactly V^T for the attention PV B-fragments).
// ---------------------------------------------------------------------------
__global__ __launch_bounds__(256) void pe_conv(const float* __restrict__ v,
                                               const float* __restrict__ Wpe,
                                               unsigned short* __restrict__ vpe)
{
    const int bc = blockIdx.x;
    const int c  = bc % C;
    const float* wp = Wpe + (size_t)c * 9;
    float wreg[9];
    #pragma unroll
    for (int i = 0; i < 9; ++i) wreg[i] = wp[i];

    const size_t base = (size_t)bc * N;
    const int tid = threadIdx.x;

    #pragma unroll
    for (int r = 0; r < 4; ++r) {
        const int pix = tid + r * 256;
        const int h = pix >> 5, w = pix & 31;
        float acc = v[base + pix];
        #pragma unroll
        for (int dh = -1; dh <= 1; ++dh) {
            const int hh = h + dh;
            if ((unsigned)hh < 32u) {
                #pragma unroll
                for (int dw = -1; dw <= 1; ++dw) {
                    const int ww = w + dw;
                    if ((unsigned)ww < 32u)
                        acc += wreg[(dh + 1) * 3 + (dw + 1)] * v[base + hh * 32 + ww];
                }
            }
        }
        vpe[base + pix] = f2bf(acc);
    }
}

// ---------------------------------------------------------------------------
// MFMA flash attention. One block per (head, be); 4 waves; wave owns 64 q-rows.
// qt,kt: bf16 [b][n][c] (q pre-scaled by 0.125). vc: bf16 [b][c][n] (=V^T).
// Online softmax over 4 KV-blocks of 64. K/V/Q fragments straight from global
// (L2-resident, no staging). Per-wave P tile through LDS (no barriers at all).
// Output: bf16 avst[b][n][c] with the torch-faithful scramble.
// ---------------------------------------------------------------------------
__global__ __launch_bounds__(256, 2) void attn_mfma(const unsigned short* __restrict__ qt,
                                                    const unsigned short* __restrict__ kt,
                                                    const unsigned short* __restrict__ vc,
                                                    unsigned short* __restrict__ avst)
{
    __shared__ float P[4][64][68];   // per-wave P tile, pad 68: 2-way-free writes

    const int tid  = threadIdx.x;
    const int lane = tid & 63;
    const int w    = tid >> 6;
    const int g    = lane >> 4;      // 16-lane group
    const int c    = lane & 15;
    const int head = blockIdx.x;
    const int be   = blockIdx.y;
    const int b = be >> 2, s = be & 3;
    const int ch0 = head * HD;
    const int t0  = s * Ne;

    const size_t qkbase = (size_t)(b * N + t0) * C + ch0;   // bf16 [n][c]
    const size_t vbase  = ((size_t)b * C + ch0) * N + t0;   // bf16 [c][n]

    // Q fragments: rows = w*64 + mi*16 + c (A-layout row = lane&15), k = d
    bf16x8 qf[4][2];
    #pragma unroll
    for (int mi = 0; mi < 4; ++mi)
        #pragma unroll
        for (int ks = 0; ks < 2; ++ks)
            qf[mi][ks] = *(const bf16x8*)&qt[qkbase +
                (size_t)(w * 64 + mi * 16 + c) * C + ks * 32 + g * 8];

    f32x4 o[4][4];
    #pragma unroll
    for (int i = 0; i < 4; ++i)
        #pragma unroll
        for (int j = 0; j < 4; ++j)
            o[i][j] = (f32x4){0.f, 0.f, 0.f, 0.f};
    float m_r[4][4], l_r[4][4];
    #pragma unroll
    for (int i = 0; i < 4; ++i)
        #pragma unroll
        for (int r = 0; r < 4; ++r) { m_r[i][r] = -1e30f; l_r[i][r] = 0.f; }

    for (int kv = 0; kv < 4; ++kv) {
        const int kv0 = kv * 64;
        // K fragments: rows = keys (S cols), k-elems = d
        bf16x8 kf[4][2];
        #pragma unroll
        for (int ni = 0; ni < 4; ++ni)
            #pragma unroll
            for (int ks = 0; ks < 2; ++ks)
                kf[ni][ks] = *(const bf16x8*)&kt[qkbase +
                    (size_t)(kv0 + ni * 16 + c) * C + ks * 32 + g * 8];

        #pragma unroll
        for (int mi = 0; mi < 4; ++mi) {
            f32x4 sa[4];
            #pragma unroll
            for (int ni = 0; ni < 4; ++ni) sa[ni] = (f32x4){0.f, 0.f, 0.f, 0.f};
            __builtin_amdgcn_s_setprio(1);
            #pragma unroll
            for (int ks = 0; ks < 2; ++ks)
                #pragma unroll
                for (int ni = 0; ni < 4; ++ni)
                    sa[ni] = __builtin_amdgcn_mfma_f32_16x16x32_bf16(
                        qf[mi][ks], kf[ni][ks], sa[ni], 0, 0, 0);
            __builtin_amdgcn_s_setprio(0);

            // online softmax per row (mi, reg r); row-group = 16 lanes
            #pragma unroll
            for (int r = 0; r < 4; ++r) {
                float tmax = fmaxf(fmaxf(sa[0][r], sa[1][r]),
                                   fmaxf(sa[2][r], sa[3][r]));
                tmax = fmaxf(tmax, __shfl_xor(tmax, 1));
                tmax = fmaxf(tmax, __shfl_xor(tmax, 2));
                tmax = fmaxf(tmax, __shfl_xor(tmax, 4));
                tmax = fmaxf(tmax, __shfl_xor(tmax, 8));
                const float mo = m_r[mi][r];
                const float mn = fmaxf(mo, tmax);
                m_r[mi][r] = mn;
                const float sc = __expf(mo - mn);
                float p0 = __expf(sa[0][r] - mn);
                float p1 = __expf(sa[1][r] - mn);
                float p2 = __expf(sa[2][r] - mn);
                float p3 = __expf(sa[3][r] - mn);
                float ps = p0 + p1 + p2 + p3;
                ps += __shfl_xor(ps, 1);
                ps += __shfl_xor(ps, 2);
                ps += __shfl_xor(ps, 4);
                ps += __shfl_xor(ps, 8);
                l_r[mi][r] = l_r[mi][r] * sc + ps;
                const int prow = mi * 16 + g * 4 + r;
                P[w][prow][c]      = p0;
                P[w][prow][16 + c] = p1;
                P[w][prow][32 + c] = p2;
                P[w][prow][48 + c] = p3;
                #pragma unroll
                for (int nj = 0; nj < 4; ++nj) o[mi][nj][r] *= sc;
            }
        }

        // PV: A = P (rows=q, k=keys), B = V^T rows=d, k=keys
        #pragma unroll
        for (int ms = 0; ms < 2; ++ms) {
            bf16x8 pa[4];
            #pragma unroll
            for (int mi = 0; mi < 4; ++mi) {
                const float* pr = &P[w][mi * 16 + c][ms * 32 + g * 8];
                const float4 a = *(const float4*)pr;
                const float4 bq = *(const float4*)(pr + 4);
                union { bf16x8 v; unsigned int u[4]; } pk;
                pk.u[0] = pack2(a.x, a.y);
                pk.u[1] = pack2(a.z, a.w);
                pk.u[2] = pack2(bq.x, bq.y);
                pk.u[3] = pack2(bq.z, bq.w);
                pa[mi] = pk.v;
            }
            bf16x8 vf[4];
            #pragma unroll
            for (int nj = 0; nj < 4; ++nj)
                vf[nj] = *(const bf16x8*)&vc[vbase +
                    (size_t)(nj * 16 + c) * N + kv0 + ms * 32 + g * 8];
            __builtin_amdgcn_s_setprio(1);
            #pragma unroll
            for (int nj = 0; nj < 4; ++nj)
                #pragma unroll
                for (int mi = 0; mi < 4; ++mi)
                    o[mi][nj] = __builtin_amdgcn_mfma_f32_16x16x32_bf16(
                        pa[mi], vf[nj], o[mi][nj], 0, 0, 0);
            __builtin_amdgcn_s_setprio(0);
        }
    }

    // normalize + scrambled scatter-store (bf16 [b][n][c])
    #pragma unroll
    for (int mi = 0; mi < 4; ++mi) {
        float inv[4];
        #pragma unroll
        for (int r = 0; r < 4; ++r) inv[r] = 1.f / l_r[mi][r];
        #pragma unroll
        for (int nj = 0; nj < 4; ++nj)
            #pragma unroll
            for (int r = 0; r < 4; ++r) {
                const float val = o[mi][nj][r] * inv[r];
                const int ne = w * 64 + mi * 16 + g * 4 + r;
                const int d  = nj * 16 + c;
                const int fl = (ch0 + d) * Ne + ne;
                const int ne2 = fl / 384;
                const int c2  = fl - ne2 * 384;
                avst[((size_t)b * N + (ne2 << 2) + s) * C + c2] = f2bf(val);
            }
    }
}

// ---------------------------------------------------------------------------
// BatchNorm stats: one block per channel, biased variance.
// ---------------------------------------------------------------------------
__global__ __launch_bounds__(256) void bnstats(const float* __restrict__ pre,
                                               float* __restrict__ mean,
                                               float* __restrict__ rstd)
{
    const int o = blockIdx.x;
    const int tid = threadIdx.x;
    float s1 = 0.f, s2 = 0.f;
    for (int idx = tid; idx < B * N; idx += 256) {
        const int bb = idx >> 10, n = idx & 1023;
        const float v = pre[((size_t)bb * C + o) * N + n];
        s1 += v;
        s2 += v * v;
    }
    #pragma unroll
    for (int off = 32; off > 0; off >>= 1) {
        s1 += __shfl_down(s1, off);
        s2 += __shfl_down(s2, off);
    }
    __shared__ float r1[4], r2[4];
    const int w = tid >> 6;
    if ((tid & 63) == 0) { r1[w] = s1; r2[w] = s2; }
    __syncthreads();
    if (tid == 0) {
        const float t1 = r1[0] + r1[1] + r1[2] + r1[3];
        const float t2 = r2[0] + r2[1] + r2[2] + r2[3];
        const float mu = t1 * (1.f / (B * N));
        const float var = t2 * (1.f / (B * N)) - mu * mu;
        mean[o] = mu;
        rstd[o] = rsqrtf(var + 1e-5f);
    }
}

// ---------------------------------------------------------------------------
// Finalize: out = x + gamma*(pre-mu)*rstd + beta
// ---------------------------------------------------------------------------
__global__ __launch_bounds__(256) void finalize(const float* __restrict__ x,
                                                const float* __restrict__ pre,
                                                const float* __restrict__ mean,
                                                const float* __restrict__ rstd,
                                                const float* __restrict__ gamma,
                                                const float* __restrict__ beta,
                                                float* __restrict__ out)
{
    const size_t i = (size_t)blockIdx.x * 256 + threadIdx.x;
    const size_t e = i << 2;
    const int c = (int)((e >> 10) % C);
    const float4 xv = *(const float4*)(x + e);
    const float4 pv = *(const float4*)(pre + e);
    const float mu = mean[c], rs = rstd[c], g = gamma[c], bt = beta[c];
    float4 o;
    o.x = xv.x + g * (pv.x - mu) * rs + bt;
    o.y = xv.y + g * (pv.y - mu) * rs + bt;
    o.z = xv.z + g * (pv.z - mu) * rs + bt;
    o.w = xv.w + g * (pv.w - mu) * rs + bt;
    *(float4*)(out + e) = o;
}

// ---------------------------------------------------------------------------
extern "C" void kernel_launch(void* const* d_in, const int* in_sizes, int n_in,
                              void* d_out, int out_size, void* d_ws, size_t ws_size,
                              hipStream_t stream)
{
    const float* x     = (const float*)d_in[0];
    const float* Wq    = (const float*)d_in[1];
    const float* Wk    = (const float*)d_in[2];
    const float* Wv    = (const float*)d_in[3];
    const float* Wpe   = (const float*)d_in[4];
    const float* Wproj = (const float*)d_in[5];
    const float* gamma = (const float*)d_in[6];
    const float* beta  = (const float*)d_in[7];
    float* out = (float*)d_out;

    float* ws = (float*)d_ws;
    const size_t SZ = (size_t)B * C * N;      // 12,582,912 elements per region

    // Region A: xt bf16 [b][n][c]  -> (after v GEMM) vc16 bf16 [b][c][n]
    // Region B: qt bf16 [b][n][c]  -> (after attn)   pre fp32 [b][c][n]
    // Region C: kt bf16 [b][n][c]
    // Region D: vb fp32 [b][c][n]  -> (after pe)     avst bf16 [b][n][c]
    float* regA = ws;
    float* regB = ws + SZ;
    float* regC = ws + 2 * SZ;
    float* regD = ws + 3 * SZ;
    unsigned short* w16 = (unsigned short*)(ws + 4 * SZ);   // 4 x 147456 bf16
    float* mean = ws + 4 * SZ + 294912;
    float* rstd = mean + C;

    unsigned short* xt   = (unsigned short*)regA;
    unsigned short* qt   = (unsigned short*)regB;
    unsigned short* kt   = (unsigned short*)regC;
    float*          vb   = regD;
    unsigned short* vc16 = (unsigned short*)regA;
    unsigned short* avst = (unsigned short*)regD;
    float*          pre  = regB;

    cast_weights<<<dim3(144, 4), 256, 0, stream>>>(Wq, Wk, Wv, Wproj, w16);
    cast_xt<<<dim3(32, 12, 32), 256, 0, stream>>>(x, xt);

    const dim3 gg(N / 128, C / 128, B);   // (8, 3, 32)
    gemm_qk<<<gg, 256, 0, stream>>>(w16,              xt, qt, 0.125f);
    gemm_qk<<<gg, 256, 0, stream>>>(w16 + 147456,     xt, kt, 1.0f);
    gemm_bt<<<gg, 256, 0, stream>>>(w16 + 2 * 147456, xt, vb);
    pe_conv<<<B * C, 256, 0, stream>>>(vb, Wpe, vc16);
    attn_mfma<<<dim3(HEADS, B * S), 256, 0, stream>>>(qt, kt, vc16, avst);
    gemm_bt<<<gg, 256, 0, stream>>>(w16 + 3 * 147456, avst, pre);
    bnstats<<<C, 256, 0, stream>>>(pre, mean, rstd);
    finalize<<<(int)(SZ / 4 / 256), 256, 0, stream>>>(x, pre, mean, rstd, gamma, beta, out);
}